// Round 13
// baseline (236.734 us; speedup 1.0000x reference)
//
#include <hip/hip_runtime.h>
#include <hip/hip_bf16.h>

// ---------------------------------------------------------------------------
// TransformerEncoder forward on MI355X (gfx950). Round 12:
//   - GEMM K-loop deepened to a 3-BUFFER pipeline: two full stages (~2 iters
//     of issue distance) stay in flight across barriers via vmcnt(2*NL).
//     Covers the ~900-cycle cold-weight HBM latency that capped MfmaUtil at
//     ~10% for rounds 8-11 (depth-2 window was ~1 iter = ~150 cycles).
//   - Buffer cycling via base + buf*STRIDE arithmetic (no runtime-indexed
//     register arrays). LDS 72/60 KB, launch_bounds(256,2).
//   - Riders / epilogues / attention / reduces identical to round 11.
// ---------------------------------------------------------------------------

typedef __bf16 bf16_t;
typedef __bf16 bf16x4 __attribute__((ext_vector_type(4)));
typedef __bf16 bf16x8 __attribute__((ext_vector_type(8)));
typedef float  f32x4  __attribute__((ext_vector_type(4)));

#define SEQL 512
#define DM   2048
#define FFH  8192
#define NH   16
#define DHD  128
#define PST  ((size_t)SEQL*DM)   // partial-slice stride

__device__ __forceinline__ unsigned short bfbits(float f){
  bf16_t h = (bf16_t)f;
  return __builtin_bit_cast(unsigned short, h);
}
__device__ __forceinline__ unsigned int pack2(float a, float b){
  return (unsigned int)bfbits(a) | ((unsigned int)bfbits(b) << 16);
}

__device__ __forceinline__ void gll16(const bf16_t* g, bf16_t* l){
  __builtin_amdgcn_global_load_lds(
      (const __attribute__((address_space(1))) void*)g,
      (__attribute__((address_space(3))) void*)l, 16, 0, 0);
}
__device__ __forceinline__ unsigned lds_off(const void* p){
  return (unsigned)(uintptr_t)(const __attribute__((address_space(3))) void*)p;
}

// ---------------------------------------------------------------------------
// Streaming fp32 -> bf16 convert, grid-stride, 2-stage register pipeline.
struct CvtSeg { const float* src; bf16_t* dst; int base; int nblk; int iters; };
struct CvtA4  { CvtSeg s[4]; };

template<int NS>
__device__ __forceinline__ void cvt_stream(const CvtSeg* segs, int b){
  int i = 0;
#pragma unroll
  for (int j = 1; j < NS; ++j) if (b >= segs[j].base) i = j;
  const float* __restrict__ src = segs[i].src;
  bf16_t* __restrict__ dst = segs[i].dst;
  const int rb = b - segs[i].base;
  const int iters = segs[i].iters;
  const size_t step = (size_t)segs[i].nblk * 8192;
  size_t off = (size_t)rb * 8192 + threadIdx.x * 8;

  f32x4 va[8], vb[8];
#define CLOAD(V, o) { _Pragma("unroll")                                     \
    for (int s2 = 0; s2 < 4; ++s2){                                         \
      V[2*s2]   = *(const f32x4*)(src + (o) + s2*2048);                     \
      V[2*s2+1] = *(const f32x4*)(src + (o) + s2*2048 + 4); } }
#define CSTORE(V, o) { _Pragma("unroll")                                    \
    for (int s2 = 0; s2 < 4; ++s2){                                         \
      uint4 u;                                                              \
      u.x = pack2(V[2*s2][0],   V[2*s2][1]);                                \
      u.y = pack2(V[2*s2][2],   V[2*s2][3]);                                \
      u.z = pack2(V[2*s2+1][0], V[2*s2+1][1]);                              \
      u.w = pack2(V[2*s2+1][2], V[2*s2+1][3]);                              \
      *(uint4*)(dst + (o) + s2*2048) = u; } }

  CLOAD(va, off);
  for (int it = 0; it < iters; ++it){
    const size_t cur = off;
    off += step;
    if (it + 1 < iters){
      if (it & 1){ CLOAD(va, off); CSTORE(vb, cur); }
      else       { CLOAD(vb, off); CSTORE(va, cur); }
    } else {
      if (it & 1){ CSTORE(vb, cur); } else { CSTORE(va, cur); }
    }
  }
#undef CLOAD
#undef CSTORE
}

template<int NS>
__global__ __launch_bounds__(256)
void cvt8k(CvtA4 a){ cvt_stream<NS>(a.s, blockIdx.x); }

// ---------------------------------------------------------------------------
// GEMM: C[512][N] = A[512][K](bf16) @ WB[K][N](bf16, HW-transposed via tr_b16).
// 3-buffer pipeline; rider blocks interleaved (rider iff (bid&RMASK)==RMASK).
constexpr int E_PART = 0;  // fp32 partial (no bias) -> outF + zt*PST
constexpr int E_QKV  = 1;  // [0,2k)->Qf flat, [2k,4k)->Kf flat, rest->Vt[h][d][key]
constexpr int E_FFN1 = 2;  // bias + gelu -> bf16 [512][FFH]

template<int EPI, int PERM, int BM, int NCVT, int RMASK, int RSHIFT>
__global__ __launch_bounds__(256, 2)
void gemmT(const bf16_t* __restrict__ A,
           const bf16_t* __restrict__ B0, const bf16_t* __restrict__ B1,
           const bf16_t* __restrict__ B2,
           const float* __restrict__ b0p, const float* __restrict__ b1p,
           const float* __restrict__ b2p,
           float* __restrict__ outF, bf16_t* __restrict__ o0,
           bf16_t* __restrict__ o1, bf16_t* __restrict__ o2,
           int nn, int Nw, int K, int Kc, int gemmN, CvtA4 cva)
{
  int bid = (int)blockIdx.x;
  if constexpr (NCVT > 0){
    if ((bid & RMASK) == RMASK){
      cvt_stream<NCVT>(cva.s, bid >> RSHIFT);
      return;
    }
    bid = (bid >> RSHIFT) * RMASK + (bid & RMASK);
  }
  constexpr int NF    = (BM == 64) ? 4 : 2;
  constexpr int APASS = BM / 32;
  constexpr int MTM   = (BM == 64) ? 7 : 15;
  constexpr int MTS   = (BM == 64) ? 3 : 4;
  constexpr unsigned ASTRIDE = (unsigned)(BM * 64 * 2);   // bytes per A buffer
  constexpr unsigned BSTRIDE = (unsigned)(128 * 64 * 2);  // bytes per B buffer
  __shared__ bf16_t sA[3][BM*64];
  __shared__ bf16_t sB[3][128*64];
  const int tid  = threadIdx.x;
  const int lane = tid & 63, w = tid >> 6;
  const int wr4 = (BM == 64) ? (w >> 1) : 0;
  const int wc  = (BM == 64) ? (w & 1)  : w;
  const int c = lane & 15, g = lane >> 4;

  // grid decode (XCD swizzle, m-fastest) over the gemm sub-grid only
  const int cpx = gemmN >> 3;
  const int sblk = (bid & 7) * cpx + (bid >> 3);
  const int mt = sblk & MTM, q2 = sblk >> MTS;
  const int nt = q2 % nn, zt = q2 / nn;
  const int m0 = mt * BM, k0 = zt * Kc;

  // weight select (QKV: three separate [2048][2048] sources)
  const bf16_t* Bsel = B0; int nb0 = nt * 128;
  if constexpr (EPI == E_QKV){
    if (nt >= 32){ Bsel = B2; nb0 = (nt - 32) * 128; }
    else if (nt >= 16){ Bsel = B1; nb0 = (nt - 16) * 128; }
  }

  // A staging
  const int arow = tid >> 3;
  const int acol = (((tid & 7) ^ ((tid >> 3) & 7)) << 3);
  const bf16_t* Aps[APASS];
#pragma unroll
  for (int pa = 0; pa < APASS; ++pa)
    Aps[pa] = A + (size_t)(m0 + pa*32 + arow) * K + k0 + acol;

  // B staging: per-lane pre-swizzled source
  const int klB  = (lane >> 3) * 4 + ((lane >> 1) & 3);
  const int colB = nb0 + w*16 + (lane & 1)*8;
  const bf16_t* Bph[2];
  if constexpr (!PERM){
#pragma unroll
    for (int h = 0; h < 2; ++h)
      Bph[h] = Bsel + (size_t)(k0 + h*32 + klB) * Nw + colB;
  }

  bf16_t* const sA0 = &sA[0][0];
  bf16_t* const sB0 = &sB[0][0];
  const unsigned sB0off = lds_off(sB0);
  const unsigned trLane = (unsigned)(g*256 + c*8);

  f32x4 acc[2][NF] = {};
  const int nk = Kc >> 6;

#define STAGE(bf, kt) {                                                     \
    bf16_t* aDst = (bf16_t*)((char*)sA0 + (unsigned)(bf)*ASTRIDE);          \
    bf16_t* bDst = (bf16_t*)((char*)sB0 + (unsigned)(bf)*BSTRIDE);          \
    _Pragma("unroll")                                                       \
    for (int pa = 0; pa < APASS; ++pa)                                      \
      gll16(Aps[pa] + (size_t)(kt)*64, aDst + (pa*256 + tid)*8);            \
    _Pragma("unroll")                                                       \
    for (int h = 0; h < 2; ++h)                                             \
      _Pragma("unroll")                                                     \
      for (int p = 0; p < 2; ++p){                                          \
        const bf16_t* src;                                                  \
        if constexpr (PERM){                                                \
          const int kr = k0 + (kt)*64 + h*32 + klB;                         \
          const int krow = ((kr & 127) << 4) + (kr >> 7);                   \
          src = Bsel + (size_t)krow * Nw + colB + p*64;                     \
        } else {                                                            \
          src = Bph[h] + (size_t)(kt)*64*Nw + p*64;                         \
        }                                                                   \
        gll16(src, bDst + h*4096 + (p*256 + tid)*8);                        \
      } }

#define COMPUTE(PB) {                                                       \
    const char* aBuf = (const char*)sA0 + (unsigned)(PB)*ASTRIDE;           \
    bf16x8 af[2][2]; bf16x8 bq[NF][2];                                      \
    _Pragma("unroll")                                                       \
    for (int m = 0; m < 2; ++m)                                             \
      _Pragma("unroll")                                                     \
      for (int ks = 0; ks < 2; ++ks){                                       \
        const int r = wr4*32 + m*16 + c;                                    \
        af[m][ks] = *(const bf16x8*)(aBuf + (r*64 + (((ks*4+g) ^ (r&7))<<3))*2); \
      }                                                                     \
    { const unsigned base = sB0off + (unsigned)(PB)*BSTRIDE                 \
                          + (unsigned)(wc*NF*1024) + trLane;                \
      _Pragma("unroll")                                                     \
      for (int n = 0; n < NF; ++n)                                          \
        _Pragma("unroll")                                                   \
        for (int ks = 0; ks < 2; ++ks){                                     \
          bf16x4 r0, r1;                                                    \
          const unsigned a2 = base + (unsigned)(n*1024 + ks*8192);          \
          asm volatile("ds_read_b64_tr_b16 %0, %1" : "=v"(r0) : "v"(a2));   \
          asm volatile("ds_read_b64_tr_b16 %0, %1 offset:128" : "=v"(r1) : "v"(a2)); \
          bq[n][ks] = __builtin_shufflevector(r0, r1, 0,1,2,3,4,5,6,7);     \
        } }                                                                 \
    asm volatile("s_waitcnt lgkmcnt(0)" ::: "memory");                      \
    __builtin_amdgcn_sched_barrier(0);                                      \
    _Pragma("unroll")                                                       \
    for (int m = 0; m < 2; ++m)                                             \
      _Pragma("unroll")                                                     \
      for (int n = 0; n < NF; ++n)                                          \
        _Pragma("unroll")                                                   \
        for (int ks = 0; ks < 2; ++ks)                                      \
          acc[m][n] = __builtin_amdgcn_mfma_f32_16x16x32_bf16(af[m][ks], bq[n][ks], acc[m][n], 0,0,0); }

  // NL = gll16s/thread/stage: 6 (BM=64) or 5 (BM=32).
#define WAIT_2STAGE() {                                                     \
    if constexpr (BM == 64) asm volatile("s_waitcnt vmcnt(12)":::"memory"); \
    else                    asm volatile("s_waitcnt vmcnt(10)":::"memory"); }
#define WAIT_1STAGE() {                                                     \
    if constexpr (BM == 64) asm volatile("s_waitcnt vmcnt(6)":::"memory");  \
    else                    asm volatile("s_waitcnt vmcnt(5)":::"memory");  }

  // prologue: 3 tiles issued; wait until tile0 lands (tiles 1,2 in flight)
  STAGE(0, 0);
  STAGE(1, 1);
  STAGE(2, 2);
  WAIT_2STAGE();
  __builtin_amdgcn_s_barrier();
  __builtin_amdgcn_sched_barrier(0);

  int buf = 0;
  for (int kt = 0; kt < nk; ++kt){
    COMPUTE(buf);
    __builtin_amdgcn_s_barrier();          // all waves done reading buf
    __builtin_amdgcn_sched_barrier(0);
    if (kt + 1 < nk){
      if (kt + 3 < nk){
        STAGE(buf, kt + 3);                // refill freed buffer
        WAIT_2STAGE();                     // kt+1 landed; kt+2, kt+3 in flight
      } else if (kt + 2 < nk){
        WAIT_1STAGE();                     // kt+1 landed; kt+2 in flight
      } else {
        asm volatile("s_waitcnt vmcnt(0)" ::: "memory");
      }
      __builtin_amdgcn_s_barrier();
      __builtin_amdgcn_sched_barrier(0);
    }
    buf = (buf == 2) ? 0 : buf + 1;
  }
#undef STAGE
#undef COMPUTE
#undef WAIT_2STAGE
#undef WAIT_1STAGE

  // epilogue
#pragma unroll
  for (int n = 0; n < NF; ++n){
    const int col = nt*128 + wc*(NF*16) + n*16 + c;
#pragma unroll
    for (int m = 0; m < 2; ++m){
      const int row0 = m0 + wr4*32 + m*16 + 4*g;
      const f32x4 a4 = acc[m][n];
      if constexpr (EPI == E_PART){
        float* dst = outF + (size_t)zt * PST;
#pragma unroll
        for (int rr = 0; rr < 4; ++rr)
          dst[(size_t)(row0+rr)*DM + col] = a4[rr];
      } else if constexpr (EPI == E_QKV){
        if (col < DM){
          const float bv = b0p[col];
#pragma unroll
          for (int rr = 0; rr < 4; ++rr)
            o0[(size_t)(row0+rr)*DM + col] = (bf16_t)(a4[rr] + bv);
        } else if (col < 2*DM){
          const int cc = col - DM;
          const float bv = b1p[cc];
#pragma unroll
          for (int rr = 0; rr < 4; ++rr)
            o1[(size_t)(row0+rr)*DM + cc] = (bf16_t)(a4[rr] + bv);
        } else {
          const int cc = col - 2*DM;
          const float bv = b2p[cc];
          const int hh = cc & 15, dd = cc >> 4;
          unsigned short us[4];
#pragma unroll
          for (int rr = 0; rr < 4; ++rr) us[rr] = bfbits(a4[rr] + bv);
          *(ushort4*)&o2[(size_t)(hh*DHD + dd)*SEQL + row0] =
              make_ushort4(us[0], us[1], us[2], us[3]);
        }
      } else if constexpr (EPI == E_FFN1){
        const float bv = b0p[col];
#pragma unroll
        for (int rr = 0; rr < 4; ++rr){
          const float v = a4[rr] + bv;
          const float z = v * (v*v*0.044715f + 1.0f) * 1.5957691216f;
          const float gg = v / (1.0f + __expf(-z));
          o0[(size_t)(row0+rr)*FFH + col] = (bf16_t)gg;
        }
      }
    }
  }
}

// ---------------------------------------------------------------------------
// Gather Q/K flat [row][16d+h] -> head layout [h][row][d] (pure bit-move).
__global__ __launch_bounds__(256)
void permute_qk(const bf16_t* __restrict__ Qf, const bf16_t* __restrict__ Kf,
                bf16_t* __restrict__ Qhd, bf16_t* __restrict__ Khd)
{
  const int row = blockIdx.x, which = blockIdx.y, tid = threadIdx.x;
  const bf16_t* src = (which ? Kf : Qf) + (size_t)row * DM;
  bf16_t* dst = which ? Khd : Qhd;
  const int hh = tid >> 4, d0 = (tid & 15) * 8;
  unsigned short us[8];
#pragma unroll
  for (int j = 0; j < 8; ++j)
    us[j] = __builtin_bit_cast(unsigned short, src[(d0 + j)*NH + hh]);
  uint4 o;
  o.x = (unsigned)us[0] | ((unsigned)us[1] << 16);
  o.y = (unsigned)us[2] | ((unsigned)us[3] << 16);
  o.z = (unsigned)us[4] | ((unsigned)us[5] << 16);
  o.w = (unsigned)us[6] | ((unsigned)us[7] << 16);
  *(uint4*)&dst[(size_t)hh*(SEQL*DHD) + (size_t)row*DHD + d0] = o;
}

// ---------------------------------------------------------------------------
// Attention (riders interleaved: rider iff (bid & RMASK) == RMASK).
template<int NCVT, int RMASK, int RSHIFT>
__global__ __launch_bounds__(256)
void attn_cvt(const bf16_t* __restrict__ Qh, const bf16_t* __restrict__ Kh,
              const bf16_t* __restrict__ Vt, bf16_t* __restrict__ Aout,
              CvtA4 cva)
{
  int bid = (int)blockIdx.x;
  if constexpr (NCVT > 0){
    if ((bid & RMASK) == RMASK){
      cvt_stream<NCVT>(cva.s, bid >> RSHIFT);
      return;
    }
    bid = (bid >> RSHIFT) * RMASK + (bid & RMASK);
  }
  __shared__ bf16_t Pl[32*512];
  __shared__ float redm[4][32];
  __shared__ float reds[4][32];
  const int tid = threadIdx.x;
  const int lane = tid & 63, w = tid >> 6;
  const int c = lane & 15, g = lane >> 4;
  const int h  = bid >> 4;
  const int rb = (bid & 15) * 32;
  const bf16_t* Qb = Qh + (size_t)h * (SEQL*DHD);
  const bf16_t* Kb = Kh + (size_t)h * (SEQL*DHD);
  const bf16_t* Vb = Vt + (size_t)h * (SEQL*DHD);

  bf16x8 qf[2][4];
#pragma unroll
  for (int a = 0; a < 2; ++a)
#pragma unroll
    for (int ks = 0; ks < 4; ++ks)
      qf[a][ks] = *(const bf16x8*)(Qb + (size_t)(rb + a*16 + c)*DHD + ks*32 + g*8);

  f32x4 s[2][8] = {};
#pragma unroll
  for (int ks = 0; ks < 4; ++ks)
#pragma unroll
    for (int b = 0; b < 8; ++b){
      const bf16x8 kf = *(const bf16x8*)(Kb + (size_t)(w*128 + b*16 + c)*DHD + ks*32 + g*8);
      s[0][b] = __builtin_amdgcn_mfma_f32_16x16x32_bf16(qf[0][ks], kf, s[0][b], 0,0,0);
      s[1][b] = __builtin_amdgcn_mfma_f32_16x16x32_bf16(qf[1][ks], kf, s[1][b], 0,0,0);
    }
#pragma unroll
  for (int a = 0; a < 2; ++a)
#pragma unroll
    for (int b = 0; b < 8; ++b)
#pragma unroll
      for (int rr = 0; rr < 4; ++rr) s[a][b][rr] *= 0.022097086912079612f;

  float mx[2][4], sm[2][4], inv[2][4];
#pragma unroll
  for (int a = 0; a < 2; ++a)
#pragma unroll
    for (int rr = 0; rr < 4; ++rr){
      float m = s[a][0][rr];
#pragma unroll
      for (int b = 1; b < 8; ++b) m = fmaxf(m, s[a][b][rr]);
#pragma unroll
      for (int off = 1; off < 16; off <<= 1) m = fmaxf(m, __shfl_xor(m, off));
      mx[a][rr] = m;
    }
  if (c == 0)
#pragma unroll
    for (int a = 0; a < 2; ++a)
#pragma unroll
      for (int rr = 0; rr < 4; ++rr) redm[w][a*16 + 4*g + rr] = mx[a][rr];
  __syncthreads();
#pragma unroll
  for (int a = 0; a < 2; ++a)
#pragma unroll
    for (int rr = 0; rr < 4; ++rr){
      const int lr = a*16 + 4*g + rr;
      mx[a][rr] = fmaxf(fmaxf(redm[0][lr], redm[1][lr]), fmaxf(redm[2][lr], redm[3][lr]));
      sm[a][rr] = 0.f;
    }
#pragma unroll
  for (int a = 0; a < 2; ++a)
#pragma unroll
    for (int b = 0; b < 8; ++b)
#pragma unroll
      for (int rr = 0; rr < 4; ++rr){
        const float p = __expf(s[a][b][rr] - mx[a][rr]);
        s[a][b][rr] = p;
        sm[a][rr] += p;
      }
#pragma unroll
  for (int a = 0; a < 2; ++a)
#pragma unroll
    for (int rr = 0; rr < 4; ++rr){
#pragma unroll
      for (int off = 1; off < 16; off <<= 1) sm[a][rr] += __shfl_xor(sm[a][rr], off);
    }
  if (c == 0)
#pragma unroll
    for (int a = 0; a < 2; ++a)
#pragma unroll
      for (int rr = 0; rr < 4; ++rr) reds[w][a*16 + 4*g + rr] = sm[a][rr];
  __syncthreads();
#pragma unroll
  for (int a = 0; a < 2; ++a)
#pragma unroll
    for (int rr = 0; rr < 4; ++rr){
      const int lr = a*16 + 4*g + rr;
      inv[a][rr] = 1.0f / (reds[0][lr] + reds[1][lr] + reds[2][lr] + reds[3][lr]);
    }

#pragma unroll
  for (int a = 0; a < 2; ++a)
#pragma unroll
    for (int b = 0; b < 8; ++b)
#pragma unroll
      for (int rr = 0; rr < 4; ++rr){
        const int lr  = a*16 + 4*g + rr;
        const int key = w*128 + b*16 + c;
        const int slot = (key >> 3) ^ (lr & 7);
        Pl[lr*512 + slot*8 + (key & 7)] = (bf16_t)(s[a][b][rr] * inv[a][rr]);
      }
  __syncthreads();

  f32x4 o[2][2] = {};
  const int dw = w * 32;
#pragma unroll
  for (int kst = 0; kst < 16; ++kst){
    bf16x8 pa2[2];
#pragma unroll
    for (int a = 0; a < 2; ++a){
      const int r = a*16 + c;
      const int slot = (kst*4 + g) ^ (r & 7);
      pa2[a] = *(const bf16x8*)&Pl[r*512 + slot*8];
    }
#pragma unroll
    for (int db = 0; db < 2; ++db){
      const bf16x8 vf = *(const bf16x8*)(Vb + (size_t)(dw + db*16 + c)*SEQL + kst*32 + g*8);
      o[0][db] = __builtin_amdgcn_mfma_f32_16x16x32_bf16(pa2[0], vf, o[0][db], 0,0,0);
      o[1][db] = __builtin_amdgcn_mfma_f32_16x16x32_bf16(pa2[1], vf, o[1][db], 0,0,0);
    }
  }
#pragma unroll
  for (int a = 0; a < 2; ++a)
#pragma unroll
    for (int db = 0; db < 2; ++db)
#pragma unroll
      for (int rr = 0; rr < 4; ++rr){
        const int row  = rb + a*16 + 4*g + rr;
        const int col2 = h*DHD + dw + db*16 + c;
        Aout[(size_t)row*DM + col2] = (bf16_t)o[a][db][rr];
      }
}

// ---------------------------------------------------------------------------
// reduce S split-K partials + bias + positional encoding -> X fp32 + XB bf16
template<int S>
__global__ __launch_bounds__(256)
void reduce_pos(const float* __restrict__ P, const float* __restrict__ bias,
                float* __restrict__ X, bf16_t* __restrict__ XB)
{
  const int row = blockIdx.x, c0 = threadIdx.x * 8;
  const size_t base = (size_t)row * DM + c0;
  float y[8];
#pragma unroll
  for (int j = 0; j < 8; ++j) y[j] = bias[c0 + j];
#pragma unroll
  for (int s = 0; s < S; ++s){
    const float4 v0 = *(const float4*)(P + s*PST + base);
    const float4 v1 = *(const float4*)(P + s*PST + base + 4);
    y[0]+=v0.x; y[1]+=v0.y; y[2]+=v0.z; y[3]+=v0.w;
    y[4]+=v1.x; y[5]+=v1.y; y[6]+=v1.z; y[7]+=v1.w;
  }
#pragma unroll
  for (int j = 0; j < 8; ++j){
    const int col = c0 + j;
    const float fr  = 1e-4f * __expf(-(float)(col >> 1) * (1.0f/1024.0f));
    const float ang = (float)row * fr;
    y[j] += (col & 1) ? __cosf(ang) : __sinf(ang);
  }
  *(float4*)(X + base)     = make_float4(y[0], y[1], y[2], y[3]);
  *(float4*)(X + base + 4) = make_float4(y[4], y[5], y[6], y[7]);
  uint4 ob;
  ob.x = pack2(y[0], y[1]); ob.y = pack2(y[2], y[3]);
  ob.z = pack2(y[4], y[5]); ob.w = pack2(y[6], y[7]);
  *(uint4*)&XB[base] = ob;
}

// ---------------------------------------------------------------------------
// reduce S split-K partials + bias + residual, then row-LayerNorm(2048).
template<int S, int WB>
__global__ __launch_bounds__(256)
void reduce_ln(const float* __restrict__ P, const float* __restrict__ bias,
               const float* __restrict__ resid, const float* __restrict__ gam,
               const float* __restrict__ bet, float* __restrict__ outF,
               bf16_t* __restrict__ outB)
{
  const int row = blockIdx.x, tid = threadIdx.x, c0 = tid * 8;
  const size_t base = (size_t)row * DM + c0;
  float y[8];
  {
    const float4 r0 = *(const float4*)(resid + base);
    const float4 r1 = *(const float4*)(resid + base + 4);
    y[0]=r0.x; y[1]=r0.y; y[2]=r0.z; y[3]=r0.w;
    y[4]=r1.x; y[5]=r1.y; y[6]=r1.z; y[7]=r1.w;
  }
#pragma unroll
  for (int j = 0; j < 8; ++j) y[j] += bias[c0 + j];
#pragma unroll
  for (int s = 0; s < S; ++s){
    const float4 v0 = *(const float4*)(P + s*PST + base);
    const float4 v1 = *(const float4*)(P + s*PST + base + 4);
    y[0]+=v0.x; y[1]+=v0.y; y[2]+=v0.z; y[3]+=v0.w;
    y[4]+=v1.x; y[5]+=v1.y; y[6]+=v1.z; y[7]+=v1.w;
  }
  float sm = 0.f, qs = 0.f;
#pragma unroll
  for (int j = 0; j < 8; ++j){ sm += y[j]; qs += y[j]*y[j]; }
#pragma unroll
  for (int off = 32; off >= 1; off >>= 1){
    sm += __shfl_xor(sm, off); qs += __shfl_xor(qs, off);
  }
  __shared__ float rs[4], rq[4];
  const int w = tid >> 6;
  if ((tid & 63) == 0){ rs[w] = sm; rq[w] = qs; }
  __syncthreads();
  sm = rs[0]+rs[1]+rs[2]+rs[3];
  qs = rq[0]+rq[1]+rq[2]+rq[3];
  const float mu   = sm * (1.0f/2048.0f);
  const float var  = qs * (1.0f/2048.0f) - mu*mu;
  const float rstd = rsqrtf(var + 1e-5f);
  const float4 g0 = *(const float4*)(gam + c0);
  const float4 g1 = *(const float4*)(gam + c0 + 4);
  const float4 b0 = *(const float4*)(bet + c0);
  const float4 b1 = *(const float4*)(bet + c0 + 4);
  float o[8];
  o[0] = (y[0]-mu)*rstd*g0.x + b0.x;  o[1] = (y[1]-mu)*rstd*g0.y + b0.y;
  o[2] = (y[2]-mu)*rstd*g0.z + b0.z;  o[3] = (y[3]-mu)*rstd*g0.w + b0.w;
  o[4] = (y[4]-mu)*rstd*g1.x + b1.x;  o[5] = (y[5]-mu)*rstd*g1.y + b1.y;
  o[6] = (y[6]-mu)*rstd*g1.z + b1.z;  o[7] = (y[7]-mu)*rstd*g1.w + b1.w;
  *(float4*)(outF + base)     = make_float4(o[0], o[1], o[2], o[3]);
  *(float4*)(outF + base + 4) = make_float4(o[4], o[5], o[6], o[7]);
  if constexpr (WB){
    uint4 ob;
    ob.x = pack2(o[0], o[1]); ob.y = pack2(o[2], o[3]);
    ob.z = pack2(o[4], o[5]); ob.w = pack2(o[6], o[7]);
    *(uint4*)&outB[base] = ob;
  }
}

// ---------------------------------------------------------------------------
extern "C" void kernel_launch(void* const* d_in, const int* in_sizes, int n_in,
                              void* d_out, int out_size, void* d_ws, size_t ws_size,
                              hipStream_t stream)
{
  const float* seq   = (const float*)d_in[0];
  const float* emb_W = (const float*)d_in[1];
  const float* emb_b = (const float*)d_in[2];
  const float* Wq = (const float*)d_in[3];  const float* bq = (const float*)d_in[4];
  const float* Wk = (const float*)d_in[5];  const float* bk = (const float*)d_in[6];
  const float* Wv = (const float*)d_in[7];  const float* bv = (const float*)d_in[8];
  const float* Wo = (const float*)d_in[9];  const float* bo = (const float*)d_in[10];
  const float* ln_g = (const float*)d_in[11]; const float* ln_b = (const float*)d_in[12];
  const float* W1 = (const float*)d_in[13]; const float* b1 = (const float*)d_in[14];
  const float* W2 = (const float*)d_in[15]; const float* b2 = (const float*)d_in[16];

  char* ws = (char*)d_ws;
  size_t off = 0;
  auto take = [&](size_t bytes) -> void* {
    void* p = ws + off;
    off += (bytes + 255) & ~(size_t)255;
    return p;
  };
  bf16_t* seqB = (bf16_t*)take((size_t)SEQL*DM*2);
  bf16_t* WeB  = (bf16_t*)take((size_t)DM*DM*2);
  bf16_t* WqB  = (bf16_t*)take((size_t)DM*DM*2);
  bf16_t* WkB  = (bf16_t*)take((size_t)DM*DM*2);
  bf16_t* WvB  = (bf16_t*)take((size_t)DM*DM*2);
  bf16_t* WoB  = (bf16_t*)take((size_t)DM*DM*2);
  bf16_t* W1B  = (bf16_t*)take((size_t)DM*FFH*2);
  bf16_t* W2B  = (bf16_t*)take((size_t)FFH*DM*2);
  float*  X    = (float*) take((size_t)SEQL*DM*4);
  bf16_t* XB   = (bf16_t*)take((size_t)SEQL*DM*2);
  bf16_t* Qf   = (bf16_t*)take((size_t)SEQL*DM*2);
  bf16_t* Kf   = (bf16_t*)take((size_t)SEQL*DM*2);
  bf16_t* Qhd  = (bf16_t*)take((size_t)SEQL*DM*2);
  bf16_t* Khd  = (bf16_t*)take((size_t)SEQL*DM*2);
  bf16_t* Vt   = (bf16_t*)take((size_t)SEQL*DM*2);
  bf16_t* Afl  = (bf16_t*)take((size_t)SEQL*DM*2);
  float*  Pp   = (float*) take((size_t)8*SEQL*DM*4);  // split-K partials (32 MB)
  float*  Xa   = (float*) take((size_t)SEQL*DM*4);
  bf16_t* XaB  = (bf16_t*)take((size_t)SEQL*DM*2);
  bf16_t* Hb   = (bf16_t*)take((size_t)SEQL*FFH*2);
  (void)ws_size; (void)in_sizes; (void)n_in; (void)out_size;

  CvtA4 cz = {};  // dummy

  // pass 0: seq (128 one-shot blocks) + emb_W (512 one-shot blocks)
  CvtA4 c0 = {};
  c0.s[0] = { seq,   seqB,   0, 128, 1 };
  c0.s[1] = { emb_W, WeB,  128, 512, 1 };
  cvt8k<2><<<dim3(640), 256, 0, stream>>>(c0);

  // embedding GEMM (512 gemm blocks) + cvt Wq/Wk/Wv/Wo (512 riders), 1:1
  CvtA4 cq = {};
  cq.s[0] = { Wq, WqB,   0, 128, 4 };
  cq.s[1] = { Wk, WkB, 128, 128, 4 };
  cq.s[2] = { Wv, WvB, 256, 128, 4 };
  cq.s[3] = { Wo, WoB, 384, 128, 4 };
  gemmT<E_PART,0,64,4,1,1><<<dim3(1024), 256, 0, stream>>>(seqB, WeB, nullptr, nullptr,
      nullptr, nullptr, nullptr, Pp, nullptr, nullptr, nullptr, 16, DM, DM, 512, 512, cq);
  reduce_pos<4><<<SEQL, 256, 0, stream>>>(Pp, emb_b, X, XB);

  // fused QKV (BM=32, 768 gemm blocks) + cvt W1 (256 riders), every 4th block
  CvtA4 c1 = {};
  c1.s[0] = { W1, W1B, 0, 256, 8 };
  gemmT<E_QKV,0,32,1,3,2><<<dim3(1024), 256, 0, stream>>>(XB, WqB, WkB, WvB,
      bq, bk, bv, nullptr, Qf, Kf, Vt, 48, DM, DM, DM, 768, c1);
  permute_qk<<<dim3(SEQL,2), 256, 0, stream>>>(Qf, Kf, Qhd, Khd);

  // attention (256 blocks) + cvt W2 (256 riders), interleaved 1:1
  CvtA4 c2 = {};
  c2.s[0] = { W2, W2B, 0, 256, 8 };
  attn_cvt<1,1,1><<<dim3(512), 256, 0, stream>>>(Qhd, Khd, Vt, Afl, c2);

  // output projection (split-K x4, k-permuted Wo rows) + residual + LN1
  gemmT<E_PART,1,64,0,0,0><<<dim3(512), 256, 0, stream>>>(Afl, WoB, nullptr, nullptr,
      nullptr, nullptr, nullptr, Pp, nullptr, nullptr, nullptr, 16, DM, DM, 512, 512, cz);
  reduce_ln<4,1><<<SEQL, 256, 0, stream>>>(Pp, bo, X, ln_g, ln_b, Xa, XaB);

  // FFN1 (BM=32, 1024 blocks)
  gemmT<E_FFN1,0,32,0,0,0><<<dim3(1024), 256, 0, stream>>>(XaB, W1B, nullptr, nullptr,
      b1, nullptr, nullptr, nullptr, Hb, nullptr, nullptr, 64, FFH, DM, DM, 1024, cz);

  // FFN2 (split-K x4, Kc=2048, 512 blocks) + residual + LN2 -> out
  gemmT<E_PART,0,64,0,0,0><<<dim3(512), 256, 0, stream>>>(Hb, W2B, nullptr, nullptr,
      nullptr, nullptr, nullptr, Pp, nullptr, nullptr, nullptr, 16, DM, FFH, 2048, 512, cz);
  reduce_ln<4,0><<<SEQL, 256, 0, stream>>>(Pp, b2, Xa, ln_g, ln_b, (float*)d_out, nullptr);
}

// Round 14
// 219.599 us; speedup vs baseline: 1.0780x; 1.0780x over previous
//
#include <hip/hip_runtime.h>
#include <hip/hip_bf16.h>

// ---------------------------------------------------------------------------
// TransformerEncoder forward on MI355X (gfx950). Round 13:
//   - GEMM K-loop reverted to round 11's depth-2 pipeline (depth-3 cost
//     occupancy 31->19% and regressed; TLP was doing the hiding).
//   - Rider cvt deepened instead: 3-stage rotating register pipeline with
//     compile-time ITERS (fully unrolled, static indices) -> 2 chunk-loads
//     (256B/thread) always in flight, ~2x per-wave streaming rate. Riders
//     were TLP-starved (host LDS caps blocks/CU); ILP is the available axis.
// ---------------------------------------------------------------------------

typedef __bf16 bf16_t;
typedef __bf16 bf16x4 __attribute__((ext_vector_type(4)));
typedef __bf16 bf16x8 __attribute__((ext_vector_type(8)));
typedef float  f32x4  __attribute__((ext_vector_type(4)));

#define SEQL 512
#define DM   2048
#define FFH  8192
#define NH   16
#define DHD  128
#define PST  ((size_t)SEQL*DM)   // partial-slice stride

__device__ __forceinline__ unsigned short bfbits(float f){
  bf16_t h = (bf16_t)f;
  return __builtin_bit_cast(unsigned short, h);
}
__device__ __forceinline__ unsigned int pack2(float a, float b){
  return (unsigned int)bfbits(a) | ((unsigned int)bfbits(b) << 16);
}

__device__ __forceinline__ void gll16(const bf16_t* g, bf16_t* l){
  __builtin_amdgcn_global_load_lds(
      (const __attribute__((address_space(1))) void*)g,
      (__attribute__((address_space(3))) void*)l, 16, 0, 0);
}
__device__ __forceinline__ unsigned lds_off(const void* p){
  return (unsigned)(uintptr_t)(const __attribute__((address_space(3))) void*)p;
}

// ---------------------------------------------------------------------------
// Streaming fp32 -> bf16 convert. 3-stage rotating register pipeline, fully
// unrolled (ITERS compile-time; all st[] indices static). One (block,iter) =
// 8192 consecutive floats; block b handles chunks rb + j*nblk, j<ITERS.
struct CvtSeg { const float* src; bf16_t* dst; int base; int nblk; };
struct CvtA4  { CvtSeg s[4]; };

template<int NS, int ITERS>
__device__ __forceinline__ void cvt_stream(const CvtSeg* segs, int b){
  int i = 0;
#pragma unroll
  for (int j = 1; j < NS; ++j) if (b >= segs[j].base) i = j;
  const float* __restrict__ src = segs[i].src;
  bf16_t* __restrict__ dst = segs[i].dst;
  const int rb = b - segs[i].base;
  const size_t step = (size_t)segs[i].nblk * 8192;
  const size_t off0 = (size_t)rb * 8192 + threadIdx.x * 8;

  f32x4 st[3][8];
#define CLOAD(V, o) { _Pragma("unroll")                                     \
    for (int s2 = 0; s2 < 4; ++s2){                                         \
      V[2*s2]   = *(const f32x4*)(src + (o) + s2*2048);                     \
      V[2*s2+1] = *(const f32x4*)(src + (o) + s2*2048 + 4); } }
#define CSTORE(V, o) { _Pragma("unroll")                                    \
    for (int s2 = 0; s2 < 4; ++s2){                                         \
      uint4 u;                                                              \
      u.x = pack2(V[2*s2][0],   V[2*s2][1]);                                \
      u.y = pack2(V[2*s2][2],   V[2*s2][3]);                                \
      u.z = pack2(V[2*s2+1][0], V[2*s2+1][1]);                              \
      u.w = pack2(V[2*s2+1][2], V[2*s2+1][3]);                              \
      *(uint4*)(dst + (o) + s2*2048) = u; } }

#pragma unroll
  for (int p = 0; p < ((ITERS < 2) ? ITERS : 2); ++p)
    CLOAD(st[p], off0 + (size_t)p*step);
#pragma unroll
  for (int it = 0; it < ITERS; ++it){
    if (it + 2 < ITERS) CLOAD(st[(it+2)%3], off0 + (size_t)(it+2)*step);
    CSTORE(st[it%3], off0 + (size_t)it*step);
  }
#undef CLOAD
#undef CSTORE
}

template<int NS, int ITERS>
__global__ __launch_bounds__(256)
void cvt8k(CvtA4 a){ cvt_stream<NS, ITERS>(a.s, blockIdx.x); }

// ---------------------------------------------------------------------------
// GEMM: C[512][N] = A[512][K](bf16) @ WB[K][N](bf16, HW-transposed via tr_b16).
// Depth-2 pipeline (round 11). Rider blocks interleaved:
// rider iff (bid & RMASK) == RMASK.
constexpr int E_PART = 0;  // fp32 partial (no bias) -> outF + zt*PST
constexpr int E_QKV  = 1;  // [0,2k)->Qf flat, [2k,4k)->Kf flat, rest->Vt[h][d][key]
constexpr int E_FFN1 = 2;  // bias + gelu -> bf16 [512][FFH]

template<int EPI, int PERM, int BM, int NCVT, int RMASK, int RSHIFT, int CIT>
__global__ __launch_bounds__(256, (BM == 64) ? 3 : 4)
void gemmT(const bf16_t* __restrict__ A,
           const bf16_t* __restrict__ B0, const bf16_t* __restrict__ B1,
           const bf16_t* __restrict__ B2,
           const float* __restrict__ b0p, const float* __restrict__ b1p,
           const float* __restrict__ b2p,
           float* __restrict__ outF, bf16_t* __restrict__ o0,
           bf16_t* __restrict__ o1, bf16_t* __restrict__ o2,
           int nn, int Nw, int K, int Kc, int gemmN, CvtA4 cva)
{
  int bid = (int)blockIdx.x;
  if constexpr (NCVT > 0){
    if ((bid & RMASK) == RMASK){
      cvt_stream<NCVT, CIT>(cva.s, bid >> RSHIFT);
      return;
    }
    bid = (bid >> RSHIFT) * RMASK + (bid & RMASK);
  }
  constexpr int NF    = (BM == 64) ? 4 : 2;
  constexpr int APASS = BM / 32;
  constexpr int MTM   = (BM == 64) ? 7 : 15;
  constexpr int MTS   = (BM == 64) ? 3 : 4;
  __shared__ bf16_t sA[2][BM*64];
  __shared__ bf16_t sB[2][128*64];
  const int tid  = threadIdx.x;
  const int lane = tid & 63, w = tid >> 6;
  const int wr4 = (BM == 64) ? (w >> 1) : 0;
  const int wc  = (BM == 64) ? (w & 1)  : w;
  const int c = lane & 15, g = lane >> 4;

  // grid decode (XCD swizzle, m-fastest) over the gemm sub-grid only
  const int cpx = gemmN >> 3;
  const int sblk = (bid & 7) * cpx + (bid >> 3);
  const int mt = sblk & MTM, q2 = sblk >> MTS;
  const int nt = q2 % nn, zt = q2 / nn;
  const int m0 = mt * BM, k0 = zt * Kc;

  // weight select (QKV: three separate [2048][2048] sources)
  const bf16_t* Bsel = B0; int nb0 = nt * 128;
  if constexpr (EPI == E_QKV){
    if (nt >= 32){ Bsel = B2; nb0 = (nt - 32) * 128; }
    else if (nt >= 16){ Bsel = B1; nb0 = (nt - 16) * 128; }
  }

  // A staging
  const int arow = tid >> 3;
  const int acol = (((tid & 7) ^ ((tid >> 3) & 7)) << 3);
  const bf16_t* Aps[APASS];
#pragma unroll
  for (int pa = 0; pa < APASS; ++pa)
    Aps[pa] = A + (size_t)(m0 + pa*32 + arow) * K + k0 + acol;

  // B staging: per-lane pre-swizzled source
  const int klB  = (lane >> 3) * 4 + ((lane >> 1) & 3);
  const int colB = nb0 + w*16 + (lane & 1)*8;
  const bf16_t* Bph[2];
  if constexpr (!PERM){
#pragma unroll
    for (int h = 0; h < 2; ++h)
      Bph[h] = Bsel + (size_t)(k0 + h*32 + klB) * Nw + colB;
  }

  const unsigned sBbase[2] = { lds_off(&sB[0][0]), lds_off(&sB[1][0]) };
  const unsigned trLane = (unsigned)(g*256 + c*8);

  f32x4 acc[2][NF] = {};
  const int nk = Kc >> 6;

#define STAGE(bf, kt) {                                                     \
    _Pragma("unroll")                                                       \
    for (int pa = 0; pa < APASS; ++pa)                                      \
      gll16(Aps[pa] + (size_t)(kt)*64, &sA[bf][(pa*256 + tid)*8]);          \
    _Pragma("unroll")                                                       \
    for (int h = 0; h < 2; ++h)                                             \
      _Pragma("unroll")                                                     \
      for (int p = 0; p < 2; ++p){                                          \
        const bf16_t* src;                                                  \
        if constexpr (PERM){                                                \
          const int kr = k0 + (kt)*64 + h*32 + klB;                         \
          const int krow = ((kr & 127) << 4) + (kr >> 7);                   \
          src = Bsel + (size_t)krow * Nw + colB + p*64;                     \
        } else {                                                            \
          src = Bph[h] + (size_t)(kt)*64*Nw + p*64;                         \
        }                                                                   \
        gll16(src, &sB[bf][h*4096 + (p*256 + tid)*8]);                      \
      } }

#define COMPUTE(PB) {                                                       \
    bf16x8 af[2][2]; bf16x8 bq[NF][2];                                      \
    _Pragma("unroll")                                                       \
    for (int m = 0; m < 2; ++m)                                             \
      _Pragma("unroll")                                                     \
      for (int ks = 0; ks < 2; ++ks){                                       \
        const int r = wr4*32 + m*16 + c;                                    \
        af[m][ks] = *(const bf16x8*)&sA[PB][r*64 + (((ks*4+g) ^ (r&7))<<3)];\
      }                                                                     \
    { const unsigned base = sBbase[PB] + (unsigned)(wc*NF*1024) + trLane;   \
      _Pragma("unroll")                                                     \
      for (int n = 0; n < NF; ++n)                                          \
        _Pragma("unroll")                                                   \
        for (int ks = 0; ks < 2; ++ks){                                     \
          bf16x4 r0, r1;                                                    \
          const unsigned a2 = base + (unsigned)(n*1024 + ks*8192);          \
          asm volatile("ds_read_b64_tr_b16 %0, %1" : "=v"(r0) : "v"(a2));   \
          asm volatile("ds_read_b64_tr_b16 %0, %1 offset:128" : "=v"(r1) : "v"(a2)); \
          bq[n][ks] = __builtin_shufflevector(r0, r1, 0,1,2,3,4,5,6,7);     \
        } }                                                                 \
    asm volatile("s_waitcnt lgkmcnt(0)" ::: "memory");                      \
    __builtin_amdgcn_sched_barrier(0);                                      \
    _Pragma("unroll")                                                       \
    for (int m = 0; m < 2; ++m)                                             \
      _Pragma("unroll")                                                     \
      for (int n = 0; n < NF; ++n)                                          \
        _Pragma("unroll")                                                   \
        for (int ks = 0; ks < 2; ++ks)                                      \
          acc[m][n] = __builtin_amdgcn_mfma_f32_16x16x32_bf16(af[m][ks], bq[n][ks], acc[m][n], 0,0,0); }

#define WAIT_NL() {                                                         \
    if constexpr (BM == 64) asm volatile("s_waitcnt vmcnt(6)" ::: "memory");\
    else                    asm volatile("s_waitcnt vmcnt(5)" ::: "memory");}

  // prologue: two tiles in flight; wait only tile0 (tile1's NL stay in flight)
  STAGE(0, 0);
  STAGE(1, 1);
  WAIT_NL();
  __builtin_amdgcn_s_barrier();
  __builtin_amdgcn_sched_barrier(0);

  int buf = 0;
  for (int kt = 0; kt < nk; ++kt){
    COMPUTE(buf);
    __builtin_amdgcn_s_barrier();          // all waves done reading buf
    __builtin_amdgcn_sched_barrier(0);
    if (kt + 1 < nk){
      if (kt + 2 < nk){
        STAGE(buf, kt + 2);                // refill freed buffer
        WAIT_NL();                         // tile kt+1 landed; kt+2 in flight
      } else {
        asm volatile("s_waitcnt vmcnt(0)" ::: "memory");
      }
      __builtin_amdgcn_s_barrier();
      __builtin_amdgcn_sched_barrier(0);
    }
    buf ^= 1;
  }
#undef STAGE
#undef COMPUTE
#undef WAIT_NL

  // epilogue
#pragma unroll
  for (int n = 0; n < NF; ++n){
    const int col = nt*128 + wc*(NF*16) + n*16 + c;
#pragma unroll
    for (int m = 0; m < 2; ++m){
      const int row0 = m0 + wr4*32 + m*16 + 4*g;
      const f32x4 a4 = acc[m][n];
      if constexpr (EPI == E_PART){
        float* dst = outF + (size_t)zt * PST;
#pragma unroll
        for (int rr = 0; rr < 4; ++rr)
          dst[(size_t)(row0+rr)*DM + col] = a4[rr];
      } else if constexpr (EPI == E_QKV){
        if (col < DM){
          const float bv = b0p[col];
#pragma unroll
          for (int rr = 0; rr < 4; ++rr)
            o0[(size_t)(row0+rr)*DM + col] = (bf16_t)(a4[rr] + bv);
        } else if (col < 2*DM){
          const int cc = col - DM;
          const float bv = b1p[cc];
#pragma unroll
          for (int rr = 0; rr < 4; ++rr)
            o1[(size_t)(row0+rr)*DM + cc] = (bf16_t)(a4[rr] + bv);
        } else {
          const int cc = col - 2*DM;
          const float bv = b2p[cc];
          const int hh = cc & 15, dd = cc >> 4;
          unsigned short us[4];
#pragma unroll
          for (int rr = 0; rr < 4; ++rr) us[rr] = bfbits(a4[rr] + bv);
          *(ushort4*)&o2[(size_t)(hh*DHD + dd)*SEQL + row0] =
              make_ushort4(us[0], us[1], us[2], us[3]);
        }
      } else if constexpr (EPI == E_FFN1){
        const float bv = b0p[col];
#pragma unroll
        for (int rr = 0; rr < 4; ++rr){
          const float v = a4[rr] + bv;
          const float z = v * (v*v*0.044715f + 1.0f) * 1.5957691216f;
          const float gg = v / (1.0f + __expf(-z));
          o0[(size_t)(row0+rr)*FFH + col] = (bf16_t)gg;
        }
      }
    }
  }
}

// ---------------------------------------------------------------------------
// Gather Q/K flat [row][16d+h] -> head layout [h][row][d] (pure bit-move).
__global__ __launch_bounds__(256)
void permute_qk(const bf16_t* __restrict__ Qf, const bf16_t* __restrict__ Kf,
                bf16_t* __restrict__ Qhd, bf16_t* __restrict__ Khd)
{
  const int row = blockIdx.x, which = blockIdx.y, tid = threadIdx.x;
  const bf16_t* src = (which ? Kf : Qf) + (size_t)row * DM;
  bf16_t* dst = which ? Khd : Qhd;
  const int hh = tid >> 4, d0 = (tid & 15) * 8;
  unsigned short us[8];
#pragma unroll
  for (int j = 0; j < 8; ++j)
    us[j] = __builtin_bit_cast(unsigned short, src[(d0 + j)*NH + hh]);
  uint4 o;
  o.x = (unsigned)us[0] | ((unsigned)us[1] << 16);
  o.y = (unsigned)us[2] | ((unsigned)us[3] << 16);
  o.z = (unsigned)us[4] | ((unsigned)us[5] << 16);
  o.w = (unsigned)us[6] | ((unsigned)us[7] << 16);
  *(uint4*)&dst[(size_t)hh*(SEQL*DHD) + (size_t)row*DHD + d0] = o;
}

// ---------------------------------------------------------------------------
// Attention (riders interleaved: rider iff (bid & RMASK) == RMASK).
template<int NCVT, int RMASK, int RSHIFT, int CIT>
__global__ __launch_bounds__(256)
void attn_cvt(const bf16_t* __restrict__ Qh, const bf16_t* __restrict__ Kh,
              const bf16_t* __restrict__ Vt, bf16_t* __restrict__ Aout,
              CvtA4 cva)
{
  int bid = (int)blockIdx.x;
  if constexpr (NCVT > 0){
    if ((bid & RMASK) == RMASK){
      cvt_stream<NCVT, CIT>(cva.s, bid >> RSHIFT);
      return;
    }
    bid = (bid >> RSHIFT) * RMASK + (bid & RMASK);
  }
  __shared__ bf16_t Pl[32*512];
  __shared__ float redm[4][32];
  __shared__ float reds[4][32];
  const int tid = threadIdx.x;
  const int lane = tid & 63, w = tid >> 6;
  const int c = lane & 15, g = lane >> 4;
  const int h  = bid >> 4;
  const int rb = (bid & 15) * 32;
  const bf16_t* Qb = Qh + (size_t)h * (SEQL*DHD);
  const bf16_t* Kb = Kh + (size_t)h * (SEQL*DHD);
  const bf16_t* Vb = Vt + (size_t)h * (SEQL*DHD);

  bf16x8 qf[2][4];
#pragma unroll
  for (int a = 0; a < 2; ++a)
#pragma unroll
    for (int ks = 0; ks < 4; ++ks)
      qf[a][ks] = *(const bf16x8*)(Qb + (size_t)(rb + a*16 + c)*DHD + ks*32 + g*8);

  f32x4 s[2][8] = {};
#pragma unroll
  for (int ks = 0; ks < 4; ++ks)
#pragma unroll
    for (int b = 0; b < 8; ++b){
      const bf16x8 kf = *(const bf16x8*)(Kb + (size_t)(w*128 + b*16 + c)*DHD + ks*32 + g*8);
      s[0][b] = __builtin_amdgcn_mfma_f32_16x16x32_bf16(qf[0][ks], kf, s[0][b], 0,0,0);
      s[1][b] = __builtin_amdgcn_mfma_f32_16x16x32_bf16(qf[1][ks], kf, s[1][b], 0,0,0);
    }
#pragma unroll
  for (int a = 0; a < 2; ++a)
#pragma unroll
    for (int b = 0; b < 8; ++b)
#pragma unroll
      for (int rr = 0; rr < 4; ++rr) s[a][b][rr] *= 0.022097086912079612f;

  float mx[2][4], sm[2][4], inv[2][4];
#pragma unroll
  for (int a = 0; a < 2; ++a)
#pragma unroll
    for (int rr = 0; rr < 4; ++rr){
      float m = s[a][0][rr];
#pragma unroll
      for (int b = 1; b < 8; ++b) m = fmaxf(m, s[a][b][rr]);
#pragma unroll
      for (int off = 1; off < 16; off <<= 1) m = fmaxf(m, __shfl_xor(m, off));
      mx[a][rr] = m;
    }
  if (c == 0)
#pragma unroll
    for (int a = 0; a < 2; ++a)
#pragma unroll
      for (int rr = 0; rr < 4; ++rr) redm[w][a*16 + 4*g + rr] = mx[a][rr];
  __syncthreads();
#pragma unroll
  for (int a = 0; a < 2; ++a)
#pragma unroll
    for (int rr = 0; rr < 4; ++rr){
      const int lr = a*16 + 4*g + rr;
      mx[a][rr] = fmaxf(fmaxf(redm[0][lr], redm[1][lr]), fmaxf(redm[2][lr], redm[3][lr]));
      sm[a][rr] = 0.f;
    }
#pragma unroll
  for (int a = 0; a < 2; ++a)
#pragma unroll
    for (int b = 0; b < 8; ++b)
#pragma unroll
      for (int rr = 0; rr < 4; ++rr){
        const float p = __expf(s[a][b][rr] - mx[a][rr]);
        s[a][b][rr] = p;
        sm[a][rr] += p;
      }
#pragma unroll
  for (int a = 0; a < 2; ++a)
#pragma unroll
    for (int rr = 0; rr < 4; ++rr){
#pragma unroll
      for (int off = 1; off < 16; off <<= 1) sm[a][rr] += __shfl_xor(sm[a][rr], off);
    }
  if (c == 0)
#pragma unroll
    for (int a = 0; a < 2; ++a)
#pragma unroll
      for (int rr = 0; rr < 4; ++rr) reds[w][a*16 + 4*g + rr] = sm[a][rr];
  __syncthreads();
#pragma unroll
  for (int a = 0; a < 2; ++a)
#pragma unroll
    for (int rr = 0; rr < 4; ++rr){
      const int lr = a*16 + 4*g + rr;
      inv[a][rr] = 1.0f / (reds[0][lr] + reds[1][lr] + reds[2][lr] + reds[3][lr]);
    }

#pragma unroll
  for (int a = 0; a < 2; ++a)
#pragma unroll
    for (int b = 0; b < 8; ++b)
#pragma unroll
      for (int rr = 0; rr < 4; ++rr){
        const int lr  = a*16 + 4*g + rr;
        const int key = w*128 + b*16 + c;
        const int slot = (key >> 3) ^ (lr & 7);
        Pl[lr*512 + slot*8 + (key & 7)] = (bf16_t)(s[a][b][rr] * inv[a][rr]);
      }
  __syncthreads();

  f32x4 o[2][2] = {};
  const int dw = w * 32;
#pragma unroll
  for (int kst = 0; kst < 16; ++kst){
    bf16x8 pa2[2];
#pragma unroll
    for (int a = 0; a < 2; ++a){
      const int r = a*16 + c;
      const int slot = (kst*4 + g) ^ (r & 7);
      pa2[a] = *(const bf16x8*)&Pl[r*512 + slot*8];
    }
#pragma unroll
    for (int db = 0; db < 2; ++db){
      const bf16x8 vf = *(const bf16x8*)(Vb + (size_t)(dw + db*16 + c)*SEQL + kst*32 + g*8);
      o[0][db] = __builtin_amdgcn_mfma_f32_16x16x32_bf16(pa2[0], vf, o[0][db], 0,0,0);
      o[1][db] = __builtin_amdgcn_mfma_f32_16x16x32_bf16(pa2[1], vf, o[1][db], 0,0,0);
    }
  }
#pragma unroll
  for (int a = 0; a < 2; ++a)
#pragma unroll
    for (int db = 0; db < 2; ++db)
#pragma unroll
      for (int rr = 0; rr < 4; ++rr){
        const int row  = rb + a*16 + 4*g + rr;
        const int col2 = h*DHD + dw + db*16 + c;
        Aout[(size_t)row*DM + col2] = (bf16_t)o[a][db][rr];
      }
}

// ---------------------------------------------------------------------------
// reduce S split-K partials + bias + positional encoding -> X fp32 + XB bf16
template<int S>
__global__ __launch_bounds__(256)
void reduce_pos(const float* __restrict__ P, const float* __restrict__ bias,
                float* __restrict__ X, bf16_t* __restrict__ XB)
{
  const int row = blockIdx.x, c0 = threadIdx.x * 8;
  const size_t base = (size_t)row * DM + c0;
  float y[8];
#pragma unroll
  for (int j = 0; j < 8; ++j) y[j] = bias[c0 + j];
#pragma unroll
  for (int s = 0; s < S; ++s){
    const float4 v0 = *(const float4*)(P + s*PST + base);
    const float4 v1 = *(const float4*)(P + s*PST + base + 4);
    y[0]+=v0.x; y[1]+=v0.y; y[2]+=v0.z; y[3]+=v0.w;
    y[4]+=v1.x; y[5]+=v1.y; y[6]+=v1.z; y[7]+=v1.w;
  }
#pragma unroll
  for (int j = 0; j < 8; ++j){
    const int col = c0 + j;
    const float fr  = 1e-4f * __expf(-(float)(col >> 1) * (1.0f/1024.0f));
    const float ang = (float)row * fr;
    y[j] += (col & 1) ? __cosf(ang) : __sinf(ang);
  }
  *(float4*)(X + base)     = make_float4(y[0], y[1], y[2], y[3]);
  *(float4*)(X + base + 4) = make_float4(y[4], y[5], y[6], y[7]);
  uint4 ob;
  ob.x = pack2(y[0], y[1]); ob.y = pack2(y[2], y[3]);
  ob.z = pack2(y[4], y[5]); ob.w = pack2(y[6], y[7]);
  *(uint4*)&XB[base] = ob;
}

// ---------------------------------------------------------------------------
// reduce S split-K partials + bias + residual, then row-LayerNorm(2048).
template<int S, int WB>
__global__ __launch_bounds__(256)
void reduce_ln(const float* __restrict__ P, const float* __restrict__ bias,
               const float* __restrict__ resid, const float* __restrict__ gam,
               const float* __restrict__ bet, float* __restrict__ outF,
               bf16_t* __restrict__ outB)
{
  const int row = blockIdx.x, tid = threadIdx.x, c0 = tid * 8;
  const size_t base = (size_t)row * DM + c0;
  float y[8];
  {
    const float4 r0 = *(const float4*)(resid + base);
    const float4 r1 = *(const float4*)(resid + base + 4);
    y[0]=r0.x; y[1]=r0.y; y[2]=r0.z; y[3]=r0.w;
    y[4]=r1.x; y[5]=r1.y; y[6]=r1.z; y[7]=r1.w;
  }
#pragma unroll
  for (int j = 0; j < 8; ++j) y[j] += bias[c0 + j];
#pragma unroll
  for (int s = 0; s < S; ++s){
    const float4 v0 = *(const float4*)(P + s*PST + base);
    const float4 v1 = *(const float4*)(P + s*PST + base + 4);
    y[0]+=v0.x; y[1]+=v0.y; y[2]+=v0.z; y[3]+=v0.w;
    y[4]+=v1.x; y[5]+=v1.y; y[6]+=v1.z; y[7]+=v1.w;
  }
  float sm = 0.f, qs = 0.f;
#pragma unroll
  for (int j = 0; j < 8; ++j){ sm += y[j]; qs += y[j]*y[j]; }
#pragma unroll
  for (int off = 32; off >= 1; off >>= 1){
    sm += __shfl_xor(sm, off); qs += __shfl_xor(qs, off);
  }
  __shared__ float rs[4], rq[4];
  const int w = tid >> 6;
  if ((tid & 63) == 0){ rs[w] = sm; rq[w] = qs; }
  __syncthreads();
  sm = rs[0]+rs[1]+rs[2]+rs[3];
  qs = rq[0]+rq[1]+rq[2]+rq[3];
  const float mu   = sm * (1.0f/2048.0f);
  const float var  = qs * (1.0f/2048.0f) - mu*mu;
  const float rstd = rsqrtf(var + 1e-5f);
  const float4 g0 = *(const float4*)(gam + c0);
  const float4 g1 = *(const float4*)(gam + c0 + 4);
  const float4 b0 = *(const float4*)(bet + c0);
  const float4 b1 = *(const float4*)(bet + c0 + 4);
  float o[8];
  o[0] = (y[0]-mu)*rstd*g0.x + b0.x;  o[1] = (y[1]-mu)*rstd*g0.y + b0.y;
  o[2] = (y[2]-mu)*rstd*g0.z + b0.z;  o[3] = (y[3]-mu)*rstd*g0.w + b0.w;
  o[4] = (y[4]-mu)*rstd*g1.x + b1.x;  o[5] = (y[5]-mu)*rstd*g1.y + b1.y;
  o[6] = (y[6]-mu)*rstd*g1.z + b1.z;  o[7] = (y[7]-mu)*rstd*g1.w + b1.w;
  *(float4*)(outF + base)     = make_float4(o[0], o[1], o[2], o[3]);
  *(float4*)(outF + base + 4) = make_float4(o[4], o[5], o[6], o[7]);
  if constexpr (WB){
    uint4 ob;
    ob.x = pack2(o[0], o[1]); ob.y = pack2(o[2], o[3]);
    ob.z = pack2(o[4], o[5]); ob.w = pack2(o[6], o[7]);
    *(uint4*)&outB[base] = ob;
  }
}

// ---------------------------------------------------------------------------
extern "C" void kernel_launch(void* const* d_in, const int* in_sizes, int n_in,
                              void* d_out, int out_size, void* d_ws, size_t ws_size,
                              hipStream_t stream)
{
  const float* seq   = (const float*)d_in[0];
  const float* emb_W = (const float*)d_in[1];
  const float* emb_b = (const float*)d_in[2];
  const float* Wq = (const float*)d_in[3];  const float* bq = (const float*)d_in[4];
  const float* Wk = (const float*)d_in[5];  const float* bk = (const float*)d_in[6];
  const float* Wv = (const float*)d_in[7];  const float* bv = (const float*)d_in[8];
  const float* Wo = (const float*)d_in[9];  const float* bo = (const float*)d_in[10];
  const float* ln_g = (const float*)d_in[11]; const float* ln_b = (const float*)d_in[12];
  const float* W1 = (const float*)d_in[13]; const float* b1 = (const float*)d_in[14];
  const float* W2 = (const float*)d_in[15]; const float* b2 = (const float*)d_in[16];

  char* ws = (char*)d_ws;
  size_t off = 0;
  auto take = [&](size_t bytes) -> void* {
    void* p = ws + off;
    off += (bytes + 255) & ~(size_t)255;
    return p;
  };
  bf16_t* seqB = (bf16_t*)take((size_t)SEQL*DM*2);
  bf16_t* WeB  = (bf16_t*)take((size_t)DM*DM*2);
  bf16_t* WqB  = (bf16_t*)take((size_t)DM*DM*2);
  bf16_t* WkB  = (bf16_t*)take((size_t)DM*DM*2);
  bf16_t* WvB  = (bf16_t*)take((size_t)DM*DM*2);
  bf16_t* WoB  = (bf16_t*)take((size_t)DM*DM*2);
  bf16_t* W1B  = (bf16_t*)take((size_t)DM*FFH*2);
  bf16_t* W2B  = (bf16_t*)take((size_t)FFH*DM*2);
  float*  X    = (float*) take((size_t)SEQL*DM*4);
  bf16_t* XB   = (bf16_t*)take((size_t)SEQL*DM*2);
  bf16_t* Qf   = (bf16_t*)take((size_t)SEQL*DM*2);
  bf16_t* Kf   = (bf16_t*)take((size_t)SEQL*DM*2);
  bf16_t* Qhd  = (bf16_t*)take((size_t)SEQL*DM*2);
  bf16_t* Khd  = (bf16_t*)take((size_t)SEQL*DM*2);
  bf16_t* Vt   = (bf16_t*)take((size_t)SEQL*DM*2);
  bf16_t* Afl  = (bf16_t*)take((size_t)SEQL*DM*2);
  float*  Pp   = (float*) take((size_t)8*SEQL*DM*4);  // split-K partials (32 MB)
  float*  Xa   = (float*) take((size_t)SEQL*DM*4);
  bf16_t* XaB  = (bf16_t*)take((size_t)SEQL*DM*2);
  bf16_t* Hb   = (bf16_t*)take((size_t)SEQL*FFH*2);
  (void)ws_size; (void)in_sizes; (void)n_in; (void)out_size;

  CvtA4 cz = {};  // dummy

  // pass 0: seq (128 one-shot blocks) + emb_W (512 one-shot blocks)
  CvtA4 c0 = {};
  c0.s[0] = { seq,   seqB,   0, 128 };
  c0.s[1] = { emb_W, WeB,  128, 512 };
  cvt8k<2,1><<<dim3(640), 256, 0, stream>>>(c0);

  // embedding GEMM (512 gemm blocks) + cvt Wq/Wk/Wv/Wo (512 riders x4), 1:1
  CvtA4 cq = {};
  cq.s[0] = { Wq, WqB,   0, 128 };
  cq.s[1] = { Wk, WkB, 128, 128 };
  cq.s[2] = { Wv, WvB, 256, 128 };
  cq.s[3] = { Wo, WoB, 384, 128 };
  gemmT<E_PART,0,64,4,1,1,4><<<dim3(1024), 256, 0, stream>>>(seqB, WeB, nullptr, nullptr,
      nullptr, nullptr, nullptr, Pp, nullptr, nullptr, nullptr, 16, DM, DM, 512, 512, cq);
  reduce_pos<4><<<SEQL, 256, 0, stream>>>(Pp, emb_b, X, XB);

  // fused QKV (BM=32, 768 gemm blocks) + cvt W1 (256 riders x8), every 4th
  CvtA4 c1 = {};
  c1.s[0] = { W1, W1B, 0, 256 };
  gemmT<E_QKV,0,32,1,3,2,8><<<dim3(1024), 256, 0, stream>>>(XB, WqB, WkB, WvB,
      bq, bk, bv, nullptr, Qf, Kf, Vt, 48, DM, DM, DM, 768, c1);
  permute_qk<<<dim3(SEQL,2), 256, 0, stream>>>(Qf, Kf, Qhd, Khd);

  // attention (256 blocks) + cvt W2 (256 riders x8), interleaved 1:1
  CvtA4 c2 = {};
  c2.s[0] = { W2, W2B, 0, 256 };
  attn_cvt<1,1,1,8><<<dim3(512), 256, 0, stream>>>(Qhd, Khd, Vt, Afl, c2);

  // output projection (split-K x4, k-permuted Wo rows) + residual + LN1
  gemmT<E_PART,1,64,0,0,0,1><<<dim3(512), 256, 0, stream>>>(Afl, WoB, nullptr, nullptr,
      nullptr, nullptr, nullptr, Pp, nullptr, nullptr, nullptr, 16, DM, DM, 512, 512, cz);
  reduce_ln<4,1><<<SEQL, 256, 0, stream>>>(Pp, bo, X, ln_g, ln_b, Xa, XaB);

  // FFN1 (BM=32, 1024 blocks)
  gemmT<E_FFN1,0,32,0,0,0,1><<<dim3(1024), 256, 0, stream>>>(XaB, W1B, nullptr, nullptr,
      b1, nullptr, nullptr, nullptr, Hb, nullptr, nullptr, 64, FFH, DM, DM, 1024, cz);

  // FFN2 (split-K x4, Kc=2048, 512 blocks) + residual + LN2 -> out
  gemmT<E_PART,0,64,0,0,0,1><<<dim3(512), 256, 0, stream>>>(Hb, W2B, nullptr, nullptr,
      nullptr, nullptr, nullptr, Pp, nullptr, nullptr, nullptr, 16, DM, FFH, 2048, 512, cz);
  reduce_ln<4,0><<<SEQL, 256, 0, stream>>>(Pp, b2, Xa, ln_g, ln_b, (float*)d_out, nullptr);
}